// Round 13
// baseline (19.752 us; speedup 1.0000x reference)
//
#include <hip/hip_runtime.h>
#include <hip/hip_bf16.h>

#define ALPHA 0.2f
constexpr int B = 8, K = 256, F = 64, E = 128;   // E = 2*F

typedef _Float16 h2 __attribute__((ext_vector_type(2)));

union H4 { uint2 u; struct { h2 lo, hi; } p; };

__device__ __forceinline__ h2 habs2(h2 v) {
    unsigned x; __builtin_memcpy(&x, &v, 4);
    x &= 0x7FFF7FFFu;
    __builtin_memcpy(&v, &x, 4);
    return v;
}

#if __has_builtin(__builtin_amdgcn_fdot2)
#define FDOT2(a, b, c) __builtin_amdgcn_fdot2((a), (b), (c), false)
#else
#define FDOT2(a, b, c) ((c) + (float)(a)[0] * (float)(b)[0] + (float)(a)[1] * (float)(b)[1])
#endif

// ---------------------------------------------------------------------------
// Workspace:
//   u_h  [B*K][E]  _Float16                                    512 KB
//   vT_h transposed v, half: idx ((b*32+e4)*K + k)*4 + (e&3)   512 KB
//   c,d  [B*K] fp32 (exact)                                    8 KB + 8 KB
//   fcp  float4 [16][64] packed fc_w                           16 KB
//   a_h  [E] _Float16 of 0.4*a                                 256 B
// ---------------------------------------------------------------------------

// kA: 256 blocks x 512 threads, 8 rows/block (thread (e, rh) does 2 rows).
// lin_w staged once per block into XOR-swizzled LDS. Block 0 packs fcp, a_h.
__global__ __launch_bounds__(512) void gat_kA(
    const float* __restrict__ x, const float* __restrict__ lin_w,
    const float* __restrict__ lin_b, const float* __restrict__ a,
    const float* __restrict__ fc_w,
    _Float16* __restrict__ u_h, _Float16* __restrict__ vT_h,
    float* __restrict__ c, float* __restrict__ d,
    float4* __restrict__ fcp, _Float16* __restrict__ a_h)
{
    const int t = threadIdx.x;               // 0..511
    const int wave = t >> 6, lane = t & 63;
    const int row0 = blockIdx.x * 8;
    const int e = t & 127, rh = t >> 7;      // rh 0..3 -> rows rh*2, rh*2+1
    const int b = row0 >> 8;

    __shared__ float4 wls[4096];             // lin_w, per-row xor-swizzled, 64 KB
    __shared__ alignas(16) float xs[8 * F];  // 8 rows of x
    __shared__ float redA[8][4];

    // ---- stage lin_w -> LDS: linear coalesced read, swizzled b128 write ----
    const float4* lw4 = (const float4*)lin_w;
#pragma unroll
    for (int i = 0; i < 8; ++i) {
        int idx = i * 512 + t;               // coalesced
        int ee = idx >> 5, cc = idx & 31;
        wls[(ee << 5) | (cc ^ (ee & 31))] = lw4[idx];
    }
    xs[t] = x[row0 * F + t];                 // 512 floats, one per thread

    if (blockIdx.x == 0) {                   // pack fc_w -> fcp, a -> a_h
#pragma unroll
        for (int i = 0; i < 2; ++i) {
            int k = i * 512 + t;
            int f4 = k >> 6, o = k & 63;
            const float* r = fc_w + o * F + f4 * 4;
            fcp[k] = make_float4(r[0], r[1], r[2], r[3]);
        }
        if (t < 128) a_h[t] = (_Float16)(0.4f * a[t]);
    }
    __syncthreads();

    // ---- main loop: 2 rows per thread; w1/w2 from swizzled LDS ----
    const int ebase = e << 5, ex = e & 31;
    float acc1[2] = {0, 0}, acc2[2] = {0, 0};
#pragma unroll
    for (int p = 0; p < 16; ++p) {
        float4 w1 = wls[ebase + (p ^ ex)];          // lin_w[e][4p..4p+3]
        float4 w2 = wls[ebase + ((16 | p) ^ ex)];   // lin_w[e][64+4p..]
#pragma unroll
        for (int r = 0; r < 2; ++r) {
            float4 xv = *(const float4*)&xs[(rh * 2 + r) * F + 4 * p];  // broadcast
            acc1[r] = fmaf(w1.x, xv.x, acc1[r]); acc1[r] = fmaf(w1.y, xv.y, acc1[r]);
            acc1[r] = fmaf(w1.z, xv.z, acc1[r]); acc1[r] = fmaf(w1.w, xv.w, acc1[r]);
            acc2[r] = fmaf(w2.x, xv.x, acc2[r]); acc2[r] = fmaf(w2.y, xv.y, acc2[r]);
            acc2[r] = fmaf(w2.z, xv.z, acc2[r]); acc2[r] = fmaf(w2.w, xv.w, acc2[r]);
        }
    }
    const float bb = lin_b[e], av = a[e];
    float vals[4];                           // {c,d} x 2 rows
#pragma unroll
    for (int r = 0; r < 2; ++r) {
        const float uu = acc1[r] + bb;
        const int rr = row0 + rh * 2 + r;
        u_h[rr * E + e] = (_Float16)uu;
        vT_h[(((b * 32) + (e >> 2)) * K + (rr & (K - 1))) * 4 + (e & 3)] =
            (_Float16)acc2[r];
        vals[r * 2 + 0] = av * acc2[r];      // c partial (fp32 exact)
        vals[r * 2 + 1] = av * uu;           // d partial
    }
#pragma unroll
    for (int off = 32; off; off >>= 1) {
#pragma unroll
        for (int q = 0; q < 4; ++q) vals[q] += __shfl_xor(vals[q], off);
    }
    if (lane == 0) {
#pragma unroll
        for (int q = 0; q < 4; ++q) redA[wave][q] = vals[q];
    }
    __syncthreads();
    if (t < 16) {
        // t -> rh2 (2b), r (1b), cd (1b); wave pair (2*rh2, 2*rh2+1) has rh=rh2
        const int rh2 = t >> 2, r = (t >> 1) & 1, cd = t & 1;
        float val = redA[rh2 * 2][r * 2 + cd] + redA[rh2 * 2 + 1][r * 2 + cd];
        const int row = row0 + rh2 * 2 + r;
        if (cd == 0) c[row] = val; else d[row] = val;
    }
}

// kB: 256 blocks x 512 threads; block = (b, 8 i-rows).
// e-loop in packed fp16 with v_dot2_f32_f16 fp32 accumulation.
__global__ __launch_bounds__(512) void gat_kB(
    const float* __restrict__ x, const _Float16* __restrict__ a_h,
    const float* __restrict__ att_bias, const float4* __restrict__ fcp,
    const float* __restrict__ fc_b, const _Float16* __restrict__ u_h,
    const uint2* __restrict__ vTh2, const float* __restrict__ c,
    const float* __restrict__ d, float* __restrict__ out)
{
    const int blk = blockIdx.x;
    const int b = blk >> 5;
    const int i0 = (blk & 31) * 8;
    const int t = threadIdx.x;
    const int wave = t >> 6, lane = t & 63;

    __shared__ float part[8][8][K];          // [e8][i][j] partial ej, 64 KB
    __shared__ float ps[8][K];               // softmax weights, 8 KB
    __shared__ float4 hpart[8][8][16];       // 16 KB
    __shared__ float4 h4s[8][16];            // 2 KB

    // ---- e-loop: wave w handles e4 in [w*4, w*4+4); 8i x 4j per thread ----
    {
        const int jj = lane;
        const uint2* v2 = vTh2 + (size_t)b * 32 * K + (size_t)wave * 4 * K + jj;
        const uint2* u2 = (const uint2*)(u_h + (size_t)(b * K + i0) * E); // uniform
        const uint2* a2 = (const uint2*)a_h;                               // uniform
        float ej[8][4];
#pragma unroll
        for (int i = 0; i < 8; ++i)
#pragma unroll
            for (int q = 0; q < 4; ++q) ej[i][q] = 0.f;

#pragma unroll
        for (int it = 0; it < 4; ++it) {
            const int e4 = wave * 4 + it;
            H4 av; av.u = a2[e4];            // wave-uniform -> s_load
            H4 vv0, vv1, vv2, vv3;
            vv0.u = v2[it * K + 0 * 64];
            vv1.u = v2[it * K + 1 * 64];
            vv2.u = v2[it * K + 2 * 64];
            vv3.u = v2[it * K + 3 * 64];
#pragma unroll
            for (int i = 0; i < 8; ++i) {
                H4 uu; uu.u = u2[i * 32 + e4];   // wave-uniform -> s_load
                {
                    h2 t0 = habs2(uu.p.lo + vv0.p.lo), t1 = habs2(uu.p.hi + vv0.p.hi);
                    ej[i][0] = FDOT2(av.p.lo, t0, ej[i][0]);
                    ej[i][0] = FDOT2(av.p.hi, t1, ej[i][0]);
                }
                {
                    h2 t0 = habs2(uu.p.lo + vv1.p.lo), t1 = habs2(uu.p.hi + vv1.p.hi);
                    ej[i][1] = FDOT2(av.p.lo, t0, ej[i][1]);
                    ej[i][1] = FDOT2(av.p.hi, t1, ej[i][1]);
                }
                {
                    h2 t0 = habs2(uu.p.lo + vv2.p.lo), t1 = habs2(uu.p.hi + vv2.p.hi);
                    ej[i][2] = FDOT2(av.p.lo, t0, ej[i][2]);
                    ej[i][2] = FDOT2(av.p.hi, t1, ej[i][2]);
                }
                {
                    h2 t0 = habs2(uu.p.lo + vv3.p.lo), t1 = habs2(uu.p.hi + vv3.p.hi);
                    ej[i][3] = FDOT2(av.p.lo, t0, ej[i][3]);
                    ej[i][3] = FDOT2(av.p.hi, t1, ej[i][3]);
                }
            }
        }
#pragma unroll
        for (int i = 0; i < 8; ++i)
#pragma unroll
            for (int q = 0; q < 4; ++q)
                part[wave][i][q * 64 + jj] = ej[i][q];
    }
    __syncthreads();

    // ---- softmax: wave w owns row i0+w; no max-sub; wave-local sum ----
    // note: a_h already contains 0.4*a, so part is the full 0.4*sum term
    {
        const int w = wave;
        const float dw = d[b * K + i0 + w];                 // uniform
        float ex[4], ssum = 0.f;
#pragma unroll
        for (int q = 0; q < 4; ++q) {
            const int j = q * 64 + lane;
            float s = part[0][w][j] + part[1][w][j] + part[2][w][j] + part[3][w][j]
                    + part[4][w][j] + part[5][w][j] + part[6][w][j] + part[7][w][j];
            float cv = c[b * K + j];                        // coalesced
            float av = att_bias[(i0 + w) * K + j];          // coalesced
            float e  = s + fmaf(0.6f, dw + cv, av);
            ex[q] = __expf(e);
            ssum += ex[q];
        }
#pragma unroll
        for (int off = 32; off; off >>= 1) ssum += __shfl_xor(ssum, off);
        const float inv = 1.f / ssum;
#pragma unroll
        for (int q = 0; q < 4; ++q) ps[w][q * 64 + lane] = ex[q] * inv;
    }
    __syncthreads();

    // ---- h-loop: thread = (jg 0..31, fq 0..15); 8 j's, 8 i-rows ----
    {
        const int jg = t >> 4, fq = t & 15;
        const float4* xb4 = (const float4*)x + (size_t)b * K * 16 + fq;
        const float4* ps4 = (const float4*)ps;      // [8][64]
        float4 h[8];
#pragma unroll
        for (int i = 0; i < 8; ++i) h[i] = make_float4(0, 0, 0, 0);
#pragma unroll
        for (int m = 0; m < 2; ++m) {
            const int j = jg * 8 + m * 4;
            float4 xa = xb4[(size_t)(j + 0) * 16];
            float4 xb = xb4[(size_t)(j + 1) * 16];
            float4 xc = xb4[(size_t)(j + 2) * 16];
            float4 xd = xb4[(size_t)(j + 3) * 16];
#pragma unroll
            for (int i = 0; i < 8; ++i) {
                float4 p = ps4[i * 64 + jg * 2 + m];
                h[i].x = fmaf(p.x, xa.x, h[i].x); h[i].y = fmaf(p.x, xa.y, h[i].y);
                h[i].z = fmaf(p.x, xa.z, h[i].z); h[i].w = fmaf(p.x, xa.w, h[i].w);
                h[i].x = fmaf(p.y, xb.x, h[i].x); h[i].y = fmaf(p.y, xb.y, h[i].y);
                h[i].z = fmaf(p.y, xb.z, h[i].z); h[i].w = fmaf(p.y, xb.w, h[i].w);
                h[i].x = fmaf(p.z, xc.x, h[i].x); h[i].y = fmaf(p.z, xc.y, h[i].y);
                h[i].z = fmaf(p.z, xc.z, h[i].z); h[i].w = fmaf(p.z, xc.w, h[i].w);
                h[i].x = fmaf(p.w, xd.x, h[i].x); h[i].y = fmaf(p.w, xd.y, h[i].y);
                h[i].z = fmaf(p.w, xd.z, h[i].z); h[i].w = fmaf(p.w, xd.w, h[i].w);
            }
        }
#pragma unroll
        for (int off = 16; off <= 32; off <<= 1) {
#pragma unroll
            for (int i = 0; i < 8; ++i) {
                h[i].x += __shfl_xor(h[i].x, off); h[i].y += __shfl_xor(h[i].y, off);
                h[i].z += __shfl_xor(h[i].z, off); h[i].w += __shfl_xor(h[i].w, off);
            }
        }
        if (lane < 16) {
#pragma unroll
            for (int i = 0; i < 8; ++i) hpart[wave][i][lane] = h[i];
        }
    }
    __syncthreads();
    if (t < 128) {
        const int i = t >> 4, f4 = t & 15;
        float4 hv = make_float4(0, 0, 0, 0);
#pragma unroll
        for (int w = 0; w < 8; ++w) {
            float4 A = hpart[w][i][f4];
            hv.x += A.x; hv.y += A.y; hv.z += A.z; hv.w += A.w;
        }
        hv.x = 1.f / (1.f + __expf(-hv.x)); hv.y = 1.f / (1.f + __expf(-hv.y));
        hv.z = 1.f / (1.f + __expf(-hv.z)); hv.w = 1.f / (1.f + __expf(-hv.w));
        h4s[i][f4] = hv;
    }
    __syncthreads();

    // ---- fc epilogue: thread = (i = wave, o = lane) ----
    {
        float acc = 0.f;
#pragma unroll
        for (int f4 = 0; f4 < 16; ++f4) {
            float4 hv = h4s[wave][f4];       // LDS broadcast
            float4 wv = fcp[f4 * 64 + lane]; // coalesced
            acc = fmaf(hv.x, wv.x, acc); acc = fmaf(hv.y, wv.y, acc);
            acc = fmaf(hv.z, wv.z, acc); acc = fmaf(hv.w, wv.w, acc);
        }
        out[(b * K + i0 + wave) * F + lane] = acc + fc_b[lane];
    }
}

extern "C" void kernel_launch(void* const* d_in, const int* in_sizes, int n_in,
                              void* d_out, int out_size, void* d_ws, size_t ws_size,
                              hipStream_t stream) {
    const float* x        = (const float*)d_in[0];
    const float* lin_w    = (const float*)d_in[1];
    const float* lin_b    = (const float*)d_in[2];
    const float* a        = (const float*)d_in[3];
    const float* att_bias = (const float*)d_in[4];
    const float* fc_w     = (const float*)d_in[5];
    const float* fc_b     = (const float*)d_in[6];
    float* out = (float*)d_out;

    _Float16* u_h  = (_Float16*)d_ws;              // 262144 halves
    _Float16* vT_h = u_h + B * K * E;              // 262144 halves
    float* c = (float*)(vT_h + B * K * E);         // 2048 fp32
    float* d = c + B * K;                          // 2048 fp32
    float4* fcp = (float4*)(d + B * K);            // 1024 float4
    _Float16* a_h = (_Float16*)(fcp + 1024);       // 128 halves

    gat_kA<<<B * K / 8, 512, 0, stream>>>(x, lin_w, lin_b, a, fc_w,
                                          u_h, vT_h, c, d, fcp, a_h);
    gat_kB<<<B * K / 8, 512, 0, stream>>>(x, a_h, att_bias, fcp, fc_b, u_h,
                                          (const uint2*)vT_h, c, d, out);
}